// Round 1
// baseline (178.907 us; speedup 1.0000x reference)
//
#include <hip/hip_runtime.h>
#include <hip/hip_bf16.h>

#define N_NODES 50000
#define N_EDGES 640000
#define N_REL   200
#define D       128
#define CAP     64              // bucket capacity; max degree ~35 (Poisson 12.8)
#define RANGES  8               // one target-range per XCD
#define NODES_PER_RANGE (N_NODES / RANGES)   // 6250
#define CHUNK_EDGES 2560
#define N_CHUNKS (N_EDGES / CHUNK_EDGES)     // 250

// fused-kernel geometry: interleave xtrans and scatter at 8-block granularity
// so scatter keeps blockIdx&7 == target-range == XCD (round-robin mapping).
#define XT_WAVES   (N_NODES / 16)            // 3125 MFMA waves
#define XT_GROUPS  98                        // ceil(ceil(3125/4)/8) blocks-of-8
#define SC_GROUPS  N_CHUNKS                  // 250 (one group = 8 ranges of a chunk)
#define TOT_GROUPS (XT_GROUPS + SC_GROUPS)   // 348 -> grid 2784 blocks

typedef __attribute__((ext_vector_type(8))) short short8;   // 8 bf16 (4 VGPRs)
typedef __attribute__((ext_vector_type(4))) float floatx4;  // MFMA acc / f32x4
typedef __attribute__((ext_vector_type(4))) unsigned uintx4;

__device__ __forceinline__ unsigned short f2bf(float f) {   // RNE f32->bf16
    unsigned u = __float_as_uint(f);
    u += 0x7FFF + ((u >> 16) & 1);
    return (unsigned short)(u >> 16);
}

__device__ __forceinline__ float sigmoidf(float x) {
    return 1.f / (1.f + __expf(-x));
}

// ---------------------------------------------------------------------------
// Kernel 1 (setup, fused by block range):
//   blocks 0..63      : W_lin -> bf16
//   blocks 64..113    : s_rel[r] = dot(rel_emb[r], W_attn)
//   blocks 114..309   : zero count[]
//   blocks 310..6559  : s_node[n] = dot(x[n], W_attn), half-wave per node
// ---------------------------------------------------------------------------
__global__ __launch_bounds__(256) void setup_kernel(
        const float* __restrict__ W,
        const float* __restrict__ x,
        const float* __restrict__ rel,
        const float* __restrict__ Wattn,
        unsigned short* __restrict__ Wbf,
        float* __restrict__ s_rel,
        float* __restrict__ s_node,
        int* __restrict__ count) {
    const int b = blockIdx.x;
    if (b < 64) {
        const int i = b * 256 + threadIdx.x;          // 0..16383
        Wbf[i] = f2bf(W[i]);
    } else if (b < 114) {
        const int wave = (b - 64) * 4 + (threadIdx.x >> 6);
        const int lane = threadIdx.x & 63;
        if (wave < N_REL) {
            const float* __restrict__ row = rel + (size_t)wave * D;
            float a = fmaf(row[lane], Wattn[lane],
                           row[lane + 64] * Wattn[lane + 64]);
#pragma unroll
            for (int off = 32; off; off >>= 1)
                a += __shfl_down(a, off);
            if (lane == 0) s_rel[wave] = a;
        }
    } else if (b < 310) {
        const int i = (b - 114) * 256 + threadIdx.x;
        if (i < N_NODES) count[i] = 0;
    } else {
        const int node = (b - 310) * 8 + (threadIdx.x >> 5);
        const int sub  = threadIdx.x & 31;
        if (node < N_NODES) {
            const float4 xv = ((const float4*)(x + (size_t)node * D))[sub];
            const float4 wv = ((const float4*)Wattn)[sub];
            float a = xv.x * wv.x + xv.y * wv.y + xv.z * wv.z + xv.w * wv.w;
#pragma unroll
            for (int off = 16; off; off >>= 1)
                a += __shfl_xor(a, off);              // within 32-lane half
            if (sub == 0) s_node[node] = a;
        }
    }
}

// ---------------------------------------------------------------------------
// Kernel 2 (FUSED): xtrans (MFMA) blocks interleaved with scatter blocks.
// Both depend only on setup and not on each other -> co-resident execution
// overlaps the MFMA-bound transform with the latency/atomic-bound scatter.
// Bresenham over 348 groups of 8 blocks keeps:
//   - scatter block b: range = b&7  (preserves XCD-local L2 writes/atomics
//     under round-robin block->XCD dispatch; correctness mapping-independent)
//   - xtrans groups spread evenly through the dispatch window.
// ---------------------------------------------------------------------------
__global__ __launch_bounds__(256) void fused_kernel(
        const float* __restrict__ x,
        const unsigned short* __restrict__ Wbf,
        unsigned short* __restrict__ xt,
        const int* __restrict__ src_idx,
        const int* __restrict__ tgt_idx,
        const int* __restrict__ etype,
        const float* __restrict__ s_node,
        const float* __restrict__ s_rel,
        int* __restrict__ count,
        unsigned* __restrict__ sorted) {
    const int g    = blockIdx.x >> 3;
    const int sub8 = blockIdx.x & 7;
    const int xg   = (g * XT_GROUPS) / TOT_GROUPS;                 // x-groups before g
    const bool is_x = (((g + 1) * XT_GROUPS) / TOT_GROUPS) > xg;   // this group is xtrans

    if (is_x) {
        // ---- xtrans: one wave per 16 nodes, MFMA 16x16x32 bf16, no LDS ----
        const int wid = (xg * 8 + sub8) * 4 + (threadIdx.x >> 6);
        if (wid >= XT_WAVES) return;               // 3133..3135 idle
        const int lane = threadIdx.x & 63;
        const int r16  = lane & 15;
        const int quad = lane >> 4;
        const int m0   = wid * 16;

        short8 af[4];
#pragma unroll
        for (int s = 0; s < 4; ++s) {
            const int k0 = s * 32 + quad * 8;
            const float* __restrict__ xr = x + (size_t)(m0 + r16) * D + k0;
            const float4 lo = *(const float4*)(xr);
            const float4 hi = *(const float4*)(xr + 4);
            short8 a;
            a[0] = (short)f2bf(lo.x); a[1] = (short)f2bf(lo.y);
            a[2] = (short)f2bf(lo.z); a[3] = (short)f2bf(lo.w);
            a[4] = (short)f2bf(hi.x); a[5] = (short)f2bf(hi.y);
            a[6] = (short)f2bf(hi.z); a[7] = (short)f2bf(hi.w);
            af[s] = a;
        }

#pragma unroll
        for (int t = 0; t < 8; ++t) {
            floatx4 acc = {0.f, 0.f, 0.f, 0.f};
#pragma unroll
            for (int s = 0; s < 4; ++s) {
                const int k0 = s * 32 + quad * 8;
                const short8 bfr = *(const short8*)(Wbf + (size_t)(t * 16 + r16) * D + k0);
                acc = __builtin_amdgcn_mfma_f32_16x16x32_bf16(af[s], bfr, acc, 0, 0, 0);
            }
#pragma unroll
            for (int r = 0; r < 4; ++r) {
                const int orow = m0 + quad * 4 + r;
                xt[(size_t)orow * D + t * 16 + r16] = f2bf(acc[r]);
            }
        }
    } else {
        // ---- scatter: chunk sg, target range sub8 (XCD-local L2 writes) ----
        const int sg   = g - xg;                    // 0..249
        const int lo   = sub8 * NODES_PER_RANGE;
        const int hi   = lo + NODES_PER_RANGE;
        const int base = sg * CHUNK_EDGES + threadIdx.x;

#pragma unroll
        for (int it = 0; it < CHUNK_EDGES / 256; ++it) {
            const int e = base + it * 256;
            // NT: edge stream is used once per XCD -> keep s_node/sorted in L2
            const int t = __builtin_nontemporal_load(tgt_idx + e);
            if (t >= lo && t < hi) {
                const int s = __builtin_nontemporal_load(src_idx + e);
                const int r = __builtin_nontemporal_load(etype + e);
                const float logit = s_node[s] + s_rel[r];
                const unsigned rec =
                    ((unsigned)f2bf(sigmoidf(logit)) << 16) | (unsigned)s;
                const int k = atomicAdd(&count[t], 1);
                sorted[t * CAP + k] = rec;          // XCD-local L2 write
            }
        }
    }
}

// ---------------------------------------------------------------------------
// Kernel 3: gather + fused ReLU. TWO nodes per wave; lane owns 4 bf16 dims.
// Records pulled 4-at-a-time (uintx4, NT) -> 4 xt row loads in flight.
// out stored nontemporally (write-once) to protect xt's L2 working set.
// ---------------------------------------------------------------------------
__device__ __forceinline__ void gproc(unsigned r, const unsigned short* __restrict__ xt,
                                      int sub, floatx4& acc) {
    const unsigned src = r & 0xFFFFu;
    const float a = __uint_as_float(r & 0xFFFF0000u);
    const uint2 p = *(const uint2*)(xt + (size_t)src * D + sub * 4);
    acc[0] = fmaf(a, __uint_as_float(p.x << 16),         acc[0]);
    acc[1] = fmaf(a, __uint_as_float(p.x & 0xFFFF0000u), acc[1]);
    acc[2] = fmaf(a, __uint_as_float(p.y << 16),         acc[2]);
    acc[3] = fmaf(a, __uint_as_float(p.y & 0xFFFF0000u), acc[3]);
}

__global__ __launch_bounds__(256) void gather_kernel(
        const int* __restrict__ count,
        const unsigned* __restrict__ sorted,
        const unsigned short* __restrict__ xt,
        float* __restrict__ out) {
    const int wid  = (blockIdx.x * blockDim.x + threadIdx.x) >> 6;
    const int lane = threadIdx.x & 63;
    const int half = lane >> 5;
    const int sub  = lane & 31;
    const int t    = wid * 2 + half;
    if (t >= N_NODES) return;

    const int cnt = count[t];
    const unsigned* __restrict__ rec = sorted + (size_t)t * CAP;

    floatx4 acc = {0.f, 0.f, 0.f, 0.f};
    int i = 0;
    for (; i + 4 <= cnt; i += 4) {
        const uintx4 r4 = __builtin_nontemporal_load((const uintx4*)(rec + i));
        gproc(r4.x, xt, sub, acc);
        gproc(r4.y, xt, sub, acc);
        gproc(r4.z, xt, sub, acc);
        gproc(r4.w, xt, sub, acc);
    }
    for (; i < cnt; ++i)
        gproc(__builtin_nontemporal_load(rec + i), xt, sub, acc);

    floatx4 o;
    o[0] = fmaxf(acc[0], 0.f);
    o[1] = fmaxf(acc[1], 0.f);
    o[2] = fmaxf(acc[2], 0.f);
    o[3] = fmaxf(acc[3], 0.f);
    __builtin_nontemporal_store(o, (floatx4*)(out + (size_t)t * D) + sub);
}

extern "C" void kernel_launch(void* const* d_in, const int* in_sizes, int n_in,
                              void* d_out, int out_size, void* d_ws, size_t ws_size,
                              hipStream_t stream) {
    const float* x        = (const float*)d_in[0];              // [N, 128]
    const int*   edge_idx = (const int*)d_in[1];                // [2, E]
    const int*   etype    = (const int*)d_in[2];                // [E]
    const float* rel_emb  = (const float*)d_in[3];              // [R, 128]
    const float* W_lin    = (const float*)d_in[4];              // [128, 128]
    const float* W_attn   = (const float*)d_in[5];              // [1, 128]
    float* out = (float*)d_out;                                 // [N, 128]

    const int* src_idx = edge_idx;
    const int* tgt_idx = edge_idx + N_EDGES;

    // workspace layout (~26 MB total)
    unsigned short* xt   = (unsigned short*)d_ws;               // 12.8 MB (bf16)
    float* s_node        = (float*)(xt + (size_t)N_NODES * D);  // 200 KB
    float* s_rel         = s_node + N_NODES;                    // 800 B
    unsigned short* Wbf  = (unsigned short*)(s_rel + N_REL);    // 32 KB (bf16)
    int*   count         = (int*)(Wbf + D * D);                 // 200 KB
    unsigned* sorted     = (unsigned*)(count + N_NODES);        // 12.8 MB

    // 1. setup: W->bf16, s_rel, zero count, s_node
    setup_kernel<<<dim3(310 + (N_NODES + 7) / 8), dim3(256), 0, stream>>>(
        W_lin, x, rel_emb, W_attn, Wbf, s_rel, s_node, count);

    // 2. FUSED xtrans (MFMA) || scatter — independent stages, co-resident.
    fused_kernel<<<dim3(TOT_GROUPS * 8), dim3(256), 0, stream>>>(
        x, Wbf, xt, src_idx, tgt_idx, etype, s_node, s_rel, count, sorted);

    // 3. gather + fused ReLU (2 nodes per wave, 8 nodes per block)
    gather_kernel<<<dim3(N_NODES / 8), dim3(256), 0, stream>>>(
        count, sorted, xt, out);
}

// Round 2
// 168.123 us; speedup vs baseline: 1.0641x; 1.0641x over previous
//
#include <hip/hip_runtime.h>
#include <hip/hip_bf16.h>

#define N_NODES 50000
#define N_EDGES 640000
#define N_REL   200
#define D       128
#define CAP     64              // bucket capacity; max degree ~35 (Poisson 12.8)
#define RANGES  8               // one target-range per XCD
#define NODES_PER_RANGE (N_NODES / RANGES)   // 6250
#define CHUNK_EDGES 2560
#define N_CHUNKS (N_EDGES / CHUNK_EDGES)     // 250

typedef __attribute__((ext_vector_type(8))) short short8;   // 8 bf16 (4 VGPRs)
typedef __attribute__((ext_vector_type(4))) float floatx4;  // MFMA acc / f32x4
typedef __attribute__((ext_vector_type(4))) unsigned uintx4;

__device__ __forceinline__ unsigned short f2bf(float f) {   // RNE f32->bf16
    unsigned u = __float_as_uint(f);
    u += 0x7FFF + ((u >> 16) & 1);
    return (unsigned short)(u >> 16);
}

__device__ __forceinline__ float sigmoidf(float x) {
    return 1.f / (1.f + __expf(-x));
}

// ---------------------------------------------------------------------------
// Kernel 1 (setup, small):
//   blocks 0..63      : W_lin -> bf16
//   blocks 64..113    : s_rel[r] = dot(rel_emb[r], W_attn)
//   blocks 114..309   : zero count[]
// (s_node moved into xtrans kernel -- saves a full 25.6 MB re-read of x)
// ---------------------------------------------------------------------------
__global__ __launch_bounds__(256) void setup_kernel(
        const float* __restrict__ W,
        const float* __restrict__ rel,
        const float* __restrict__ Wattn,
        unsigned short* __restrict__ Wbf,
        float* __restrict__ s_rel,
        int* __restrict__ count) {
    const int b = blockIdx.x;
    if (b < 64) {
        const int i = b * 256 + threadIdx.x;          // 0..16383
        Wbf[i] = f2bf(W[i]);
    } else if (b < 114) {
        const int wave = (b - 64) * 4 + (threadIdx.x >> 6);
        const int lane = threadIdx.x & 63;
        if (wave < N_REL) {
            const float* __restrict__ row = rel + (size_t)wave * D;
            float a = fmaf(row[lane], Wattn[lane],
                           row[lane + 64] * Wattn[lane + 64]);
#pragma unroll
            for (int off = 32; off; off >>= 1)
                a += __shfl_down(a, off);
            if (lane == 0) s_rel[wave] = a;
        }
    } else {
        const int i = (b - 114) * 256 + threadIdx.x;
        if (i < N_NODES) count[i] = 0;
    }
}

// ---------------------------------------------------------------------------
// Kernel 2: xt = x @ W_lin.T via MFMA 16x16x32 bf16, one wave per 16 nodes.
// FUSED: s_node[n] = dot(x[n], W_attn) computed from the same f32 registers
// before bf16 conversion (32 fma/lane + 2 shfl_xor) -- x is read exactly once.
// ---------------------------------------------------------------------------
__global__ __launch_bounds__(256) void xtrans_mfma_kernel(
        const float* __restrict__ x,
        const unsigned short* __restrict__ Wbf,
        const float* __restrict__ Wattn,
        unsigned short* __restrict__ xt,
        float* __restrict__ s_node) {
    const int wid = (blockIdx.x * blockDim.x + threadIdx.x) >> 6;
    if (wid >= N_NODES / 16) return;           // 3125 waves exactly
    const int lane = threadIdx.x & 63;
    const int r16  = lane & 15;
    const int quad = lane >> 4;
    const int m0   = wid * 16;

    short8 af[4];
    float  sn = 0.f;                            // partial dot(x[row], W_attn)
#pragma unroll
    for (int s = 0; s < 4; ++s) {
        const int k0 = s * 32 + quad * 8;
        const float* __restrict__ xr = x + (size_t)(m0 + r16) * D + k0;
        const float4 lo = *(const float4*)(xr);
        const float4 hi = *(const float4*)(xr + 4);
        const float4 wl = *(const float4*)(Wattn + k0);
        const float4 wh = *(const float4*)(Wattn + k0 + 4);
        sn = fmaf(lo.x, wl.x, sn); sn = fmaf(lo.y, wl.y, sn);
        sn = fmaf(lo.z, wl.z, sn); sn = fmaf(lo.w, wl.w, sn);
        sn = fmaf(hi.x, wh.x, sn); sn = fmaf(hi.y, wh.y, sn);
        sn = fmaf(hi.z, wh.z, sn); sn = fmaf(hi.w, wh.w, sn);
        short8 a;
        a[0] = (short)f2bf(lo.x); a[1] = (short)f2bf(lo.y);
        a[2] = (short)f2bf(lo.z); a[3] = (short)f2bf(lo.w);
        a[4] = (short)f2bf(hi.x); a[5] = (short)f2bf(hi.y);
        a[6] = (short)f2bf(hi.z); a[7] = (short)f2bf(hi.w);
        af[s] = a;
    }
    // reduce across the 4 quad-lanes holding row m0+r16
    sn += __shfl_xor(sn, 16);
    sn += __shfl_xor(sn, 32);
    if (lane < 16) s_node[m0 + r16] = sn;      // 64B coalesced per wave

#pragma unroll
    for (int t = 0; t < 8; ++t) {
        floatx4 acc = {0.f, 0.f, 0.f, 0.f};
#pragma unroll
        for (int s = 0; s < 4; ++s) {
            const int k0 = s * 32 + quad * 8;
            const short8 b = *(const short8*)(Wbf + (size_t)(t * 16 + r16) * D + k0);
            acc = __builtin_amdgcn_mfma_f32_16x16x32_bf16(af[s], b, acc, 0, 0, 0);
        }
#pragma unroll
        for (int r = 0; r < 4; ++r) {
            const int orow = m0 + quad * 4 + r;
            xt[(size_t)orow * D + t * 16 + r16] = f2bf(acc[r]);
        }
    }
}

// ---------------------------------------------------------------------------
// Kernel 3: XCD-partitioned bucket scatter (standalone again -- fusing xtrans
// into this kernel in R1 streamed x/xt through the XCD-local L2s and evicted
// the dirty sorted/count slices: WRITE_SIZE 38.8MB vs 18MB expected).
// Plain (cached) edge loads: the 8 range-blocks of a chunk are blockIdx-
// adjacent -> land on 8 XCDs nearly simultaneously -> L3 serves 7/8 re-reads.
// tgt/src/etype loaded unconditionally & coalesced so the unrolled loop's 30
// loads can all be hoisted & in flight; s_rel staged in LDS (one less L2 hop
// in the per-edge dependent chain).
// ---------------------------------------------------------------------------
__global__ __launch_bounds__(256) void scatter_kernel(
        const int* __restrict__ src_idx,
        const int* __restrict__ tgt_idx,
        const int* __restrict__ etype,
        const float* __restrict__ s_node,
        const float* __restrict__ s_rel,
        int* __restrict__ count,
        unsigned* __restrict__ sorted) {
    __shared__ float ls_rel[N_REL];
    if (threadIdx.x < N_REL) ls_rel[threadIdx.x] = s_rel[threadIdx.x];
    __syncthreads();

    const int b     = blockIdx.x;
    const int lo    = (b & 7) * NODES_PER_RANGE;
    const int hi    = lo + NODES_PER_RANGE;
    const int base  = (b >> 3) * CHUNK_EDGES + threadIdx.x;

#pragma unroll
    for (int it = 0; it < CHUNK_EDGES / 256; ++it) {
        const int e = base + it * 256;
        const int t = tgt_idx[e];                    // coalesced
        const int s = src_idx[e];                    // coalesced, unconditional
        const int r = etype[e];                      // coalesced, unconditional
        if (t >= lo && t < hi) {
            const float logit = s_node[s] + ls_rel[r];
            const unsigned rec =
                ((unsigned)f2bf(sigmoidf(logit)) << 16) | (unsigned)s;
            const int k = atomicAdd(&count[t], 1);
            sorted[t * CAP + k] = rec;               // XCD-local L2 write
        }
    }
}

// ---------------------------------------------------------------------------
// Kernel 4: gather + fused ReLU. TWO nodes per wave; lane owns 4 bf16 dims.
// Records pulled 4-at-a-time (uintx4, NT: single-use) -> 4 xt rows in flight.
// out stored nontemporally (write-once) to protect xt's L2 working set.
// ---------------------------------------------------------------------------
__device__ __forceinline__ void gproc(unsigned r, const unsigned short* __restrict__ xt,
                                      int sub, floatx4& acc) {
    const unsigned src = r & 0xFFFFu;
    const float a = __uint_as_float(r & 0xFFFF0000u);
    const uint2 p = *(const uint2*)(xt + (size_t)src * D + sub * 4);
    acc[0] = fmaf(a, __uint_as_float(p.x << 16),         acc[0]);
    acc[1] = fmaf(a, __uint_as_float(p.x & 0xFFFF0000u), acc[1]);
    acc[2] = fmaf(a, __uint_as_float(p.y << 16),         acc[2]);
    acc[3] = fmaf(a, __uint_as_float(p.y & 0xFFFF0000u), acc[3]);
}

__global__ __launch_bounds__(256) void gather_kernel(
        const int* __restrict__ count,
        const unsigned* __restrict__ sorted,
        const unsigned short* __restrict__ xt,
        float* __restrict__ out) {
    const int wid  = (blockIdx.x * blockDim.x + threadIdx.x) >> 6;
    const int lane = threadIdx.x & 63;
    const int half = lane >> 5;
    const int sub  = lane & 31;
    const int t    = wid * 2 + half;
    if (t >= N_NODES) return;

    const int cnt = count[t];
    const unsigned* __restrict__ rec = sorted + (size_t)t * CAP;

    floatx4 acc = {0.f, 0.f, 0.f, 0.f};
    int i = 0;
    for (; i + 4 <= cnt; i += 4) {
        const uintx4 r4 = __builtin_nontemporal_load((const uintx4*)(rec + i));
        gproc(r4.x, xt, sub, acc);
        gproc(r4.y, xt, sub, acc);
        gproc(r4.z, xt, sub, acc);
        gproc(r4.w, xt, sub, acc);
    }
    for (; i < cnt; ++i)
        gproc(__builtin_nontemporal_load(rec + i), xt, sub, acc);

    floatx4 o;
    o[0] = fmaxf(acc[0], 0.f);
    o[1] = fmaxf(acc[1], 0.f);
    o[2] = fmaxf(acc[2], 0.f);
    o[3] = fmaxf(acc[3], 0.f);
    __builtin_nontemporal_store(o, (floatx4*)(out + (size_t)t * D) + sub);
}

extern "C" void kernel_launch(void* const* d_in, const int* in_sizes, int n_in,
                              void* d_out, int out_size, void* d_ws, size_t ws_size,
                              hipStream_t stream) {
    const float* x        = (const float*)d_in[0];              // [N, 128]
    const int*   edge_idx = (const int*)d_in[1];                // [2, E]
    const int*   etype    = (const int*)d_in[2];                // [E]
    const float* rel_emb  = (const float*)d_in[3];              // [R, 128]
    const float* W_lin    = (const float*)d_in[4];              // [128, 128]
    const float* W_attn   = (const float*)d_in[5];              // [1, 128]
    float* out = (float*)d_out;                                 // [N, 128]

    const int* src_idx = edge_idx;
    const int* tgt_idx = edge_idx + N_EDGES;

    // workspace layout (~26 MB total)
    unsigned short* xt   = (unsigned short*)d_ws;               // 12.8 MB (bf16)
    float* s_node        = (float*)(xt + (size_t)N_NODES * D);  // 200 KB
    float* s_rel         = s_node + N_NODES;                    // 800 B
    unsigned short* Wbf  = (unsigned short*)(s_rel + N_REL);    // 32 KB (bf16)
    int*   count         = (int*)(Wbf + D * D);                 // 200 KB
    unsigned* sorted     = (unsigned*)(count + N_NODES);        // 12.8 MB

    // 1. setup: W->bf16, s_rel, zero count  (tiny)
    setup_kernel<<<dim3(310), dim3(256), 0, stream>>>(
        W_lin, rel_emb, W_attn, Wbf, s_rel, count);

    // 2. xt = x @ W_lin.T (MFMA) + fused s_node = x @ W_attn.T
    xtrans_mfma_kernel<<<dim3((N_NODES / 16 * 64 + 255) / 256), dim3(256), 0, stream>>>(
        x, Wbf, W_attn, xt, s_node);

    // 3. XCD-partitioned bucket scatter (2000 blocks = 250 chunks x 8 ranges)
    scatter_kernel<<<dim3(N_CHUNKS * RANGES), dim3(256), 0, stream>>>(
        src_idx, tgt_idx, etype, s_node, s_rel, count, sorted);

    // 4. gather + fused ReLU (2 nodes per wave, 8 nodes per block)
    gather_kernel<<<dim3(N_NODES / 8), dim3(256), 0, stream>>>(
        count, sorted, xt, out);
}

// Round 4
// 155.479 us; speedup vs baseline: 1.1507x; 1.0813x over previous
//
#include <hip/hip_runtime.h>
#include <hip/hip_bf16.h>

#define N_NODES 50000
#define N_EDGES 640000
#define N_REL   200
#define D       128
#define CAP     64              // bucket capacity; max degree ~35 (Poisson 12.8)
#define RANGES  8               // one target-range per XCD
#define NODES_PER_RANGE (N_NODES / RANGES)   // 6250
#define CHUNK_EDGES 2560
#define N_CHUNKS (N_EDGES / CHUNK_EDGES)     // 250

// pre_kernel block ranges
#define XT_WAVES   (N_NODES / 16)            // 3125
#define XT_BLOCKS  782                       // ceil(3125/4)
#define SREL_BLOCKS 50                       // 200 waves
#define CNT_BLOCKS 196                       // 50176 threads >= N_NODES
#define PRE_BLOCKS (XT_BLOCKS + SREL_BLOCKS + CNT_BLOCKS)

// gather geometry: 4 nodes per wave, XCD-matched (blockIdx&7 == range)
#define G_BLOCKS_PER_RANGE 391               // ceil(6250/16)

typedef __attribute__((ext_vector_type(8))) short short8;   // 8 bf16 (4 VGPRs)
typedef __attribute__((ext_vector_type(4))) float floatx4;  // MFMA acc / f32x4
typedef __attribute__((ext_vector_type(4))) unsigned uintx4;

__device__ __forceinline__ unsigned short f2bf(float f) {   // RNE f32->bf16
    unsigned u = __float_as_uint(f);
    u += 0x7FFF + ((u >> 16) & 1);
    return (unsigned short)(u >> 16);
}

__device__ __forceinline__ float sigmoidf(float x) {
    return 1.f / (1.f + __expf(-x));
}

// ---------------------------------------------------------------------------
// Kernel 1 (pre): everything before scatter, one kernel, no dependencies.
//   blocks 0..781   : xtrans via MFMA. W converted f32->bf16 into a 32 KB
//                     XOR-swizzled LDS tile per block (kills Wbf round-trip
//                     and the setup->xtrans launch dependency). Fused s_node.
//   blocks 782..831 : s_rel[r] = dot(rel_emb[r], W_attn)
//   blocks 832..1027: zero count[]
// LDS swizzle: 16B slot index (row*16 + k0/8) ^ (row&7); bijective per row,
// spreads the 16 r16-lanes of each ds_read_b128 over 8 bank-groups (= the
// wave64 b128 floor).
// ---------------------------------------------------------------------------
__global__ __launch_bounds__(256) void pre_kernel(
        const float* __restrict__ x,
        const float* __restrict__ W,
        const float* __restrict__ rel,
        const float* __restrict__ Wattn,
        unsigned short* __restrict__ xt,
        float* __restrict__ s_node,
        float* __restrict__ s_rel,
        int* __restrict__ count) {
    __shared__ unsigned short lw[D * D];      // 32 KB swizzled bf16 W
    const int b = blockIdx.x;

    if (b < XT_BLOCKS) {
        // ---- stage W into swizzled LDS (all 256 threads) ----
        const int tid = threadIdx.x;
#pragma unroll
        for (int i = 0; i < 8; ++i) {
            const int idx8 = tid + i * 256;           // 8-element group id
            const int row  = idx8 >> 4;               // 0..127
            const int kk   = idx8 & 15;               // k0/8
            const float* __restrict__ wr = W + (size_t)row * D + kk * 8;
            const float4 lo = *(const float4*)(wr);
            const float4 hi = *(const float4*)(wr + 4);
            short8 v;
            v[0] = (short)f2bf(lo.x); v[1] = (short)f2bf(lo.y);
            v[2] = (short)f2bf(lo.z); v[3] = (short)f2bf(lo.w);
            v[4] = (short)f2bf(hi.x); v[5] = (short)f2bf(hi.y);
            v[6] = (short)f2bf(hi.z); v[7] = (short)f2bf(hi.w);
            const int slot = (row * 16 + kk) ^ (row & 7);
            *(short8*)((char*)lw + slot * 16) = v;
        }
        __syncthreads();

        const int wid = b * 4 + (threadIdx.x >> 6);
        if (wid >= XT_WAVES) return;               // last 3 waves idle
        const int lane = threadIdx.x & 63;
        const int r16  = lane & 15;
        const int quad = lane >> 4;
        const int m0   = wid * 16;

        short8 af[4];
        float  sn = 0.f;                            // dot(x[row], W_attn)
#pragma unroll
        for (int s = 0; s < 4; ++s) {
            const int k0 = s * 32 + quad * 8;
            const float* __restrict__ xr = x + (size_t)(m0 + r16) * D + k0;
            const float4 lo = *(const float4*)(xr);
            const float4 hi = *(const float4*)(xr + 4);
            const float4 wl = *(const float4*)(Wattn + k0);
            const float4 wh = *(const float4*)(Wattn + k0 + 4);
            sn = fmaf(lo.x, wl.x, sn); sn = fmaf(lo.y, wl.y, sn);
            sn = fmaf(lo.z, wl.z, sn); sn = fmaf(lo.w, wl.w, sn);
            sn = fmaf(hi.x, wh.x, sn); sn = fmaf(hi.y, wh.y, sn);
            sn = fmaf(hi.z, wh.z, sn); sn = fmaf(hi.w, wh.w, sn);
            short8 a;
            a[0] = (short)f2bf(lo.x); a[1] = (short)f2bf(lo.y);
            a[2] = (short)f2bf(lo.z); a[3] = (short)f2bf(lo.w);
            a[4] = (short)f2bf(hi.x); a[5] = (short)f2bf(hi.y);
            a[6] = (short)f2bf(hi.z); a[7] = (short)f2bf(hi.w);
            af[s] = a;
        }
        sn += __shfl_xor(sn, 16);
        sn += __shfl_xor(sn, 32);
        if (lane < 16) s_node[m0 + r16] = sn;      // 64B coalesced per wave

#pragma unroll
        for (int t = 0; t < 8; ++t) {
            floatx4 acc = {0.f, 0.f, 0.f, 0.f};
            const int row = t * 16 + r16;
#pragma unroll
            for (int s = 0; s < 4; ++s) {
                const int slot = (row * 16 + s * 4 + quad) ^ (row & 7);
                const short8 bfrag = *(const short8*)((const char*)lw + slot * 16);
                acc = __builtin_amdgcn_mfma_f32_16x16x32_bf16(af[s], bfrag, acc, 0, 0, 0);
            }
#pragma unroll
            for (int r = 0; r < 4; ++r) {
                const int orow = m0 + quad * 4 + r;
                xt[(size_t)orow * D + t * 16 + r16] = f2bf(acc[r]);
            }
        }
    } else if (b < XT_BLOCKS + SREL_BLOCKS) {
        const int wave = (b - XT_BLOCKS) * 4 + (threadIdx.x >> 6);
        const int lane = threadIdx.x & 63;
        if (wave < N_REL) {
            const float* __restrict__ row = rel + (size_t)wave * D;
            float a = fmaf(row[lane], Wattn[lane],
                           row[lane + 64] * Wattn[lane + 64]);
#pragma unroll
            for (int off = 32; off; off >>= 1)
                a += __shfl_down(a, off);
            if (lane == 0) s_rel[wave] = a;
        }
    } else {
        const int i = (b - XT_BLOCKS - SREL_BLOCKS) * 256 + threadIdx.x;
        if (i < N_NODES) count[i] = 0;
    }
}

// ---------------------------------------------------------------------------
// Kernel 2: XCD-partitioned bucket scatter (unchanged from R2: proven).
// ---------------------------------------------------------------------------
__global__ __launch_bounds__(256) void scatter_kernel(
        const int* __restrict__ src_idx,
        const int* __restrict__ tgt_idx,
        const int* __restrict__ etype,
        const float* __restrict__ s_node,
        const float* __restrict__ s_rel,
        int* __restrict__ count,
        unsigned* __restrict__ sorted) {
    __shared__ float ls_rel[N_REL];
    if (threadIdx.x < N_REL) ls_rel[threadIdx.x] = s_rel[threadIdx.x];
    __syncthreads();

    const int b     = blockIdx.x;
    const int lo    = (b & 7) * NODES_PER_RANGE;
    const int hi    = lo + NODES_PER_RANGE;
    const int base  = (b >> 3) * CHUNK_EDGES + threadIdx.x;

#pragma unroll
    for (int it = 0; it < CHUNK_EDGES / 256; ++it) {
        const int e = base + it * 256;
        const int t = tgt_idx[e];                    // coalesced
        const int s = src_idx[e];                    // coalesced, unconditional
        const int r = etype[e];                      // coalesced, unconditional
        if (t >= lo && t < hi) {
            const float logit = s_node[s] + ls_rel[r];
            const unsigned rec =
                ((unsigned)f2bf(sigmoidf(logit)) << 16) | (unsigned)s;
            const int k = atomicAdd(&count[t], 1);
            sorted[t * CAP + k] = rec;               // XCD-local L2 write
        }
    }
}

// ---------------------------------------------------------------------------
// Kernel 3: gather + fused ReLU. FOUR nodes per wave (16 lanes each, uint4 =
// 16B/lane): one xt-load instruction now covers 4 rows (1 KB) instead of 2
// (512B) -> VMEM instruction count halved, wave-iterations 365K -> ~206K.
// XCD-matched: blockIdx&7 == node range == the XCD whose scatter wrote these
// count/sorted lines (clean-retained L2 lines hit instead of L3).
// ---------------------------------------------------------------------------
__device__ __forceinline__ void gproc4(unsigned r, const unsigned short* __restrict__ xt,
                                       int sub, floatx4& a0, floatx4& a1) {
    const unsigned src = r & 0xFFFFu;
    const float a = __uint_as_float(r & 0xFFFF0000u);
    const uint4 p = *(const uint4*)(xt + (size_t)src * D + sub * 8);
    a0[0] = fmaf(a, __uint_as_float(p.x << 16),         a0[0]);
    a0[1] = fmaf(a, __uint_as_float(p.x & 0xFFFF0000u), a0[1]);
    a0[2] = fmaf(a, __uint_as_float(p.y << 16),         a0[2]);
    a0[3] = fmaf(a, __uint_as_float(p.y & 0xFFFF0000u), a0[3]);
    a1[0] = fmaf(a, __uint_as_float(p.z << 16),         a1[0]);
    a1[1] = fmaf(a, __uint_as_float(p.z & 0xFFFF0000u), a1[1]);
    a1[2] = fmaf(a, __uint_as_float(p.w << 16),         a1[2]);
    a1[3] = fmaf(a, __uint_as_float(p.w & 0xFFFF0000u), a1[3]);
}

__global__ __launch_bounds__(256) void gather_kernel(
        const int* __restrict__ count,
        const unsigned* __restrict__ sorted,
        const unsigned short* __restrict__ xt,
        float* __restrict__ out) {
    const int rng   = blockIdx.x & 7;
    const int idx   = blockIdx.x >> 3;               // 0..390
    const int w     = threadIdx.x >> 6;
    const int lane  = threadIdx.x & 63;
    const int q     = lane >> 4;
    const int sub   = lane & 15;
    const int local = idx * 16 + w * 4 + q;
    if (local >= NODES_PER_RANGE) return;
    const int t = rng * NODES_PER_RANGE + local;

    const int cnt = count[t];
    const unsigned* __restrict__ rec = sorted + (size_t)t * CAP;

    floatx4 a0 = {0.f, 0.f, 0.f, 0.f};
    floatx4 a1 = {0.f, 0.f, 0.f, 0.f};
    int i = 0;
    for (; i + 4 <= cnt; i += 4) {
        const uintx4 r4 = __builtin_nontemporal_load((const uintx4*)(rec + i));
        gproc4(r4.x, xt, sub, a0, a1);
        gproc4(r4.y, xt, sub, a0, a1);
        gproc4(r4.z, xt, sub, a0, a1);
        gproc4(r4.w, xt, sub, a0, a1);
    }
    for (; i < cnt; ++i)
        gproc4(__builtin_nontemporal_load(rec + i), xt, sub, a0, a1);

    floatx4 o0, o1;
    o0[0] = fmaxf(a0[0], 0.f); o0[1] = fmaxf(a0[1], 0.f);
    o0[2] = fmaxf(a0[2], 0.f); o0[3] = fmaxf(a0[3], 0.f);
    o1[0] = fmaxf(a1[0], 0.f); o1[1] = fmaxf(a1[1], 0.f);
    o1[2] = fmaxf(a1[2], 0.f); o1[3] = fmaxf(a1[3], 0.f);
    floatx4* orow = (floatx4*)(out + (size_t)t * D) + sub * 2;
    __builtin_nontemporal_store(o0, orow);
    __builtin_nontemporal_store(o1, orow + 1);
}

extern "C" void kernel_launch(void* const* d_in, const int* in_sizes, int n_in,
                              void* d_out, int out_size, void* d_ws, size_t ws_size,
                              hipStream_t stream) {
    const float* x        = (const float*)d_in[0];              // [N, 128]
    const int*   edge_idx = (const int*)d_in[1];                // [2, E]
    const int*   etype    = (const int*)d_in[2];                // [E]
    const float* rel_emb  = (const float*)d_in[3];              // [R, 128]
    const float* W_lin    = (const float*)d_in[4];              // [128, 128]
    const float* W_attn   = (const float*)d_in[5];              // [1, 128]
    float* out = (float*)d_out;                                 // [N, 128]

    const int* src_idx = edge_idx;
    const int* tgt_idx = edge_idx + N_EDGES;

    // workspace layout (~26 MB total, Wbf eliminated)
    unsigned short* xt   = (unsigned short*)d_ws;               // 12.8 MB (bf16)
    float* s_node        = (float*)(xt + (size_t)N_NODES * D);  // 200 KB
    float* s_rel         = s_node + N_NODES;                    // 800 B
    int*   count         = (int*)(s_rel + N_REL);               // 200 KB
    unsigned* sorted     = (unsigned*)(count + N_NODES);        // 12.8 MB

    // 1. pre: xtrans(MFMA, W->LDS) + s_node + s_rel + count-zero, one kernel
    pre_kernel<<<dim3(PRE_BLOCKS), dim3(256), 0, stream>>>(
        x, W_lin, rel_emb, W_attn, xt, s_node, s_rel, count);

    // 2. XCD-partitioned bucket scatter (2000 blocks = 250 chunks x 8 ranges)
    scatter_kernel<<<dim3(N_CHUNKS * RANGES), dim3(256), 0, stream>>>(
        src_idx, tgt_idx, etype, s_node, s_rel, count, sorted);

    // 3. gather + fused ReLU (4 nodes per wave, XCD-matched)
    gather_kernel<<<dim3(G_BLOCKS_PER_RANGE * RANGES), dim3(256), 0, stream>>>(
        count, sorted, xt, out);
}